// Round 13
// baseline (576.731 us; speedup 1.0000x reference)
//
#include <hip/hip_runtime.h>
#include <math.h>

#define N_NODES 200000
#define N_EDGES 6400000
#define N_GRAPHS 2048
#define HID 32
#define BN_EPS 1e-5f

#define NPB 256                                   // nodes per bucket (pow2) for part/sort
#define NBUCK ((N_NODES + NPB - 1) / NPB)         // 782
#define CAP 8960                                  // mean 8184 + ~8.6 sigma; 8960/256 = 35
#define PART_CHUNK 8192
#define NPARTBLK ((N_EDGES + PART_CHUNK - 1) / PART_CHUNK)  // 782

#define NPC 64                                    // nodes per conv2 block
#define NBLK_C (N_NODES / NPC)                    // 3125 (exact)
#define AGS 36                                    // aggL stride: 16B-aligned float4 rows

#define RED_BLKS 64                               // stage-1 reduction blocks for part2
#define RED_CHUNK ((NBLK_C + RED_BLKS - 1) / RED_BLKS)  // 49

__device__ inline float relu_f(float v) { return fmaxf(v, 0.f); }

// ---------------- cursor init ----------------
__global__ void k_init(int* __restrict__ cursor) {
    int t = blockIdx.x * blockDim.x + threadIdx.x;
    if (t < NBUCK) cursor[t] = t * CAP;
}

// ---------------- bucket partition: edges -> packed (src | local_dst<<18) ----------------
// int4 loads; rank captured in pass-1 histogram atomics -> pass-2 scatter is atomic-free.
__launch_bounds__(256)
__global__ void k_part(const int* __restrict__ src, const int* __restrict__ dst,
                       int* __restrict__ cursor, unsigned int* __restrict__ ebuf) {
    __shared__ int histL[NBUCK];
    __shared__ int baseL[NBUCK];
    int tid = threadIdx.x;
    for (int i = tid; i < NBUCK; i += 256) histL[i] = 0;
    __syncthreads();
    int e0 = blockIdx.x * PART_CHUNK;
    int e1 = min(e0 + PART_CHUNK, N_EDGES);
    int4 dreg[8];
    int4 rreg[8];
    // pass 1: histogram with rank capture (dst cached in registers)
#pragma unroll
    for (int i = 0; i < 8; i++) {
        int base = e0 + (i * 256 + tid) * 4;
        if (base < e1) {   // base,e1 both 4-aligned -> full int4 or nothing
            int4 d4 = *(const int4*)(dst + base);
            dreg[i] = d4;
            rreg[i].x = atomicAdd(&histL[d4.x >> 8], 1);
            rreg[i].y = atomicAdd(&histL[d4.y >> 8], 1);
            rreg[i].z = atomicAdd(&histL[d4.z >> 8], 1);
            rreg[i].w = atomicAdd(&histL[d4.w >> 8], 1);
        } else {
            dreg[i] = make_int4(-1, -1, -1, -1);
        }
    }
    __syncthreads();
    for (int i = tid; i < NBUCK; i += 256) {
        int c = histL[i];
        if (c) baseL[i] = atomicAdd(&cursor[i], c);
    }
    __syncthreads();
    // pass 2: scatter packed records (no atomics)
#pragma unroll
    for (int i = 0; i < 8; i++) {
        int base = e0 + (i * 256 + tid) * 4;
        if (base < e1) {
            int4 s4 = *(const int4*)(src + base);
            int4 d4 = dreg[i];
            int4 r4 = rreg[i];
            int b, pos;
            b = d4.x >> 8; pos = baseL[b] + r4.x;
            if (pos < (b + 1) * CAP) ebuf[pos] = (unsigned)(s4.x & 0x3FFFF) | ((unsigned)(d4.x & 255) << 18);
            b = d4.y >> 8; pos = baseL[b] + r4.y;
            if (pos < (b + 1) * CAP) ebuf[pos] = (unsigned)(s4.y & 0x3FFFF) | ((unsigned)(d4.y & 255) << 18);
            b = d4.z >> 8; pos = baseL[b] + r4.z;
            if (pos < (b + 1) * CAP) ebuf[pos] = (unsigned)(s4.z & 0x3FFFF) | ((unsigned)(d4.z & 255) << 18);
            b = d4.w >> 8; pos = baseL[b] + r4.w;
            if (pos < (b + 1) * CAP) ebuf[pos] = (unsigned)(s4.w & 0x3FFFF) | ((unsigned)(d4.w & 255) << 18);
        }
    }
}

// ---------------- counting sort within bucket + per-node x-sum + BN1 partials ----------------
// Rank captured in pass-1 histogram atomics -> scatter is atomic-free.
__launch_bounds__(256)
__global__ void k_sort(const unsigned int* __restrict__ ebuf, const int* __restrict__ cursor,
                       const float* __restrict__ x, int* __restrict__ ebuf2,
                       int* __restrict__ deg, int* __restrict__ offs,
                       float* __restrict__ ax, float* __restrict__ part1) {
    __shared__ int degL[NPB], scanL[NPB], offL[NPB];
    __shared__ float red[4][5];
    int tid = threadIdx.x;
    degL[tid] = 0;
    __syncthreads();
    int b = blockIdx.x;
    int p0 = b * CAP;
    int cnt = min(cursor[b] - p0, CAP);
    int rk[35];   // CAP/256 = 35
    // pass 1: histogram with rank capture
#pragma unroll
    for (int it = 0; it < 35; it++) {
        int i = tid + it * 256;
        if (i < cnt) rk[it] = atomicAdd(&degL[ebuf[p0 + i] >> 18], 1);
    }
    __syncthreads();
    int d = degL[tid];
    scanL[tid] = d;
    __syncthreads();
    for (int off = 1; off < NPB; off <<= 1) {
        int y = (tid >= off) ? scanL[tid - off] : 0;
        __syncthreads();
        scanL[tid] += y;
        __syncthreads();
    }
    int myoff = scanL[tid] - d;  // exclusive prefix
    offL[tid] = myoff;
    __syncthreads();
    int node = b * NPB + tid;
    if (node < N_NODES) { deg[node] = d; offs[node] = p0 + myoff; }
    // pass 2: scatter with captured ranks (ebuf re-read, L2-hot; no atomics)
#pragma unroll
    for (int it = 0; it < 35; it++) {
        int i = tid + it * 256;
        if (i < cnt) {
            unsigned v = ebuf[p0 + i];
            int ld = v >> 18;
            ebuf2[p0 + offL[ld] + rk[it]] = (int)(v & 0x3FFFF);
        }
    }
    __syncthreads();
    // per-node serial sum of x over sorted neighbor list (L2-hot, just written by this block)
    float sum = 0.f;
    int base = p0 + myoff;
    int j = 0;
    for (; j + 8 <= d; j += 8) {
        int ss[8];
#pragma unroll
        for (int k = 0; k < 8; k++) ss[k] = ebuf2[base + j + k];
        float acc = 0.f;
#pragma unroll
        for (int k = 0; k < 8; k++) acc += x[ss[k]];
        sum += acc;
    }
    for (; j < d; j++) sum += x[ebuf2[base + j]];
    float an = 0.f, xn = 0.f;
    if (node < N_NODES) {
        an = sum / (float)max(d, 1);
        xn = x[node];
        ax[2 * node] = an;
        ax[2 * node + 1] = xn;
    }
    float sa = an, sx = xn, saa = an * an, sxx = xn * xn, sax = an * xn;
    for (int o = 32; o; o >>= 1) {
        sa += __shfl_down(sa, o);
        sx += __shfl_down(sx, o);
        saa += __shfl_down(saa, o);
        sxx += __shfl_down(sxx, o);
        sax += __shfl_down(sax, o);
    }
    int w = tid >> 6;
    if ((tid & 63) == 0) {
        red[w][0] = sa; red[w][1] = sx; red[w][2] = saa; red[w][3] = sxx; red[w][4] = sax;
    }
    __syncthreads();
    if (tid < 5)
        part1[b * 8 + tid] = red[0][tid] + red[1][tid] + red[2][tid] + red[3][tid];
}

// ---------------- fold BN1: parallel fp64 reduction of partials ----------------
__launch_bounds__(256)
__global__ void k_params1(const float* __restrict__ part1,
                          const float* __restrict__ W1l, const float* __restrict__ b1l,
                          const float* __restrict__ W1r, const float* __restrict__ g1,
                          const float* __restrict__ be1, float* __restrict__ pABC) {
    int tid = threadIdx.x;
    double loc[5] = {0, 0, 0, 0, 0};
    for (int b = tid; b < NBUCK; b += 256) {
#pragma unroll
        for (int s = 0; s < 5; s++) loc[s] += (double)part1[b * 8 + s];
    }
    for (int o = 32; o; o >>= 1) {
#pragma unroll
        for (int s = 0; s < 5; s++) loc[s] += __shfl_down(loc[s], o);
    }
    __shared__ double red[4][5];
    __shared__ double st[5];
    int w = tid >> 6;
    if ((tid & 63) == 0) {
#pragma unroll
        for (int s = 0; s < 5; s++) red[w][s] = loc[s];
    }
    __syncthreads();
    if (tid < 5) st[tid] = red[0][tid] + red[1][tid] + red[2][tid] + red[3][tid];
    __syncthreads();
    int f = tid;
    if (f < HID) {
        double invN = 1.0 / (double)N_NODES;
        double ma = st[0] * invN, mx = st[1] * invN;
        double va = st[2] * invN - ma * ma;
        double vx = st[3] * invN - mx * mx;
        double cax = st[4] * invN - ma * mx;
        double wl = (double)W1l[f], wr = (double)W1r[f];
        double mu = wl * ma + wr * mx + (double)b1l[f];
        double var = wl * wl * va + wr * wr * vx + 2.0 * wl * wr * cax;
        double s = (double)g1[f] / sqrt(var + (double)BN_EPS);
        pABC[f] = (float)(wl * s);
        pABC[HID + f] = (float)(wr * s);
        pABC[2 * HID + f] = (float)(((double)b1l[f] - mu) * s + (double)be1[f]);
    }
}

// ---------------- conv2: stage-gather-then-crunch + low-VGPR matmul + BN2 partials ----------
// __launch_bounds__(256,8): force VGPR<=64 so 8 waves/SIMD can co-reside (68 VGPR halved occ).
__launch_bounds__(256, 8)
__global__ void k_conv2(const int* __restrict__ ebuf2, const int* __restrict__ offs,
                        const int* __restrict__ deg, const float* __restrict__ ax,
                        const float* __restrict__ pABC,
                        const float* __restrict__ W2l, const float* __restrict__ W2r,
                        const float* __restrict__ b2l, float* __restrict__ h2pre,
                        float* __restrict__ part2) {
    __shared__ __align__(16) float aggL[NPC * AGS];   // stride 36 -> 16B-aligned rows (9 KB)
    __shared__ __align__(16) float2 pairL[8 * 32];    // per-group gather staging (2 KB)
    __shared__ float A_s[HID], B_s[HID], C_s[HID];
    __shared__ int degS[NPC], offS[NPC];
    int tid = threadIdx.x;
    int b = blockIdx.x;
    if (tid < HID) {
        A_s[tid] = pABC[tid];
        B_s[tid] = pABC[HID + tid];
        C_s[tid] = pABC[2 * HID + tid];
    }
    if (tid < NPC) {
        degS[tid] = deg[b * NPC + tid];
        offS[tid] = offs[b * NPC + tid];
    }
    __syncthreads();
    int f = tid & 31;                         // lane within group = feature in crunch
    int grp = tid >> 5;                       // 8 groups of 32 lanes
    float Af = A_s[f], Bf = B_s[f], Cf = C_s[f];
    const float2* ax2 = (const float2*)ax;
    float2* myStage = pairL + grp * 32;
    const float4* myStage4 = (const float4*)myStage;
    // Phase A: per node, stage 32 pairs via ONE coalesced idx load + ONE 32-wide gather,
    // then crunch from LDS (lane = feature, broadcast reads).
#pragma unroll 1
    for (int i = 0; i < NPC / 8; i++) {
        int ln = i * 8 + grp;
        int dg = degS[ln], off = offS[ln];
        float m = 0.f;
#pragma unroll 1
        for (int j = 0; j < dg; j += 32) {
            int rem = min(32, dg - j);
            float2 pv = make_float2(0.f, 0.f);
            if (f < rem) pv = ax2[ebuf2[off + j + f]];   // 32 independent gathers in flight
            myStage[f] = pv;
            int k = 0;
            for (; k + 2 <= rem; k += 2) {
                float4 q = myStage4[k >> 1];             // broadcast LDS read, 2 edges
                m += relu_f(fmaf(q.x, Af, fmaf(q.y, Bf, Cf)));
                m += relu_f(fmaf(q.z, Af, fmaf(q.w, Bf, Cf)));
            }
            if (k < rem) {
                float2 q = myStage[k];
                m += relu_f(fmaf(q.x, Af, fmaf(q.y, Bf, Cf)));
            }
        }
        aggL[ln * AGS + f] = m / (float)max(dg, 1);
    }
    __syncthreads();
    // Phase B: thread = (node = tid&63, feature octet = tid>>6). Low-VGPR: stream ag from
    // LDS in float4 chunks, recompute h1 4-at-a-time; weights via wave-uniform loads.
    int nl = tid & 63;
    int fg = tid >> 6;                        // 0..3, uniform per wave
    int node = b * NPC + nl;
    float2 axn = ax2[node];
    float an = axn.x, xn = axn.y;
    float v[8];
#pragma unroll
    for (int lf = 0; lf < 8; lf++) v[lf] = b2l[fg * 8 + lf];
#pragma unroll
    for (int q = 0; q < HID / 4; q++) {
        float4 ag4 = *(const float4*)&aggL[nl * AGS + 4 * q];
        float4 h14;
        h14.x = relu_f(fmaf(an, A_s[4 * q],     fmaf(xn, B_s[4 * q],     C_s[4 * q])));
        h14.y = relu_f(fmaf(an, A_s[4 * q + 1], fmaf(xn, B_s[4 * q + 1], C_s[4 * q + 1])));
        h14.z = relu_f(fmaf(an, A_s[4 * q + 2], fmaf(xn, B_s[4 * q + 2], C_s[4 * q + 2])));
        h14.w = relu_f(fmaf(an, A_s[4 * q + 3], fmaf(xn, B_s[4 * q + 3], C_s[4 * q + 3])));
#pragma unroll
        for (int lf = 0; lf < 8; lf++) {
            int ff = fg * 8 + lf;
            float4 wl = *(const float4*)(W2l + ff * HID + 4 * q);   // wave-uniform
            float4 wr = *(const float4*)(W2r + ff * HID + 4 * q);
            float s = v[lf];
            s = fmaf(ag4.x, wl.x, fmaf(h14.x, wr.x, s));
            s = fmaf(ag4.y, wl.y, fmaf(h14.y, wr.y, s));
            s = fmaf(ag4.z, wl.z, fmaf(h14.z, wr.z, s));
            s = fmaf(ag4.w, wl.w, fmaf(h14.w, wr.w, s));
            v[lf] = s;
        }
    }
    // store: 4 threads per node cover the contiguous 32-float row (2 float4 each)
    float4* op = (float4*)(h2pre + (size_t)node * HID + fg * 8);
    op[0] = make_float4(v[0], v[1], v[2], v[3]);
    op[1] = make_float4(v[4], v[5], v[6], v[7]);
    // BN2 partials: wave-level reduce over 64 nodes for this wave's 8 features
#pragma unroll
    for (int lf = 0; lf < 8; lf++) {
        float s1v = v[lf], s2v = v[lf] * v[lf];
        for (int o = 32; o; o >>= 1) {
            s1v += __shfl_down(s1v, o);
            s2v += __shfl_down(s2v, o);
        }
        if (nl == 0) {
            part2[(size_t)b * 64 + fg * 8 + lf] = s1v;
            part2[(size_t)b * 64 + 32 + fg * 8 + lf] = s2v;
        }
    }
}

// ---------------- BN2 reduction stage 1: 64 blocks sum slices of part2 (fp64) ----------------
__launch_bounds__(256)
__global__ void k_red2(const float* __restrict__ part2, double* __restrict__ mid) {
    __shared__ double st2[4][64];
    int tid = threadIdx.x;
    int q = tid >> 6, t = tid & 63;
    int b0 = blockIdx.x * RED_CHUNK;
    int b1 = min(b0 + RED_CHUNK, NBLK_C);
    double s = 0.0;
    for (int b = b0 + q; b < b1; b += 4) s += (double)part2[(size_t)b * 64 + t];
    st2[q][t] = s;
    __syncthreads();
    if (tid < 64)
        mid[(size_t)blockIdx.x * 64 + tid] = st2[0][tid] + st2[1][tid] + st2[2][tid] + st2[3][tid];
}

// ---------------- fold BN2: stage 2 over 64x64 doubles ----------------
__launch_bounds__(256)
__global__ void k_params2(const double* __restrict__ mid, const float* __restrict__ g2,
                          const float* __restrict__ be2, float* __restrict__ pPQ) {
    __shared__ double st2[4][64];
    __shared__ double st[64];
    int tid = threadIdx.x;
    int q = tid >> 6, t = tid & 63;
    double s = 0.0;
    for (int i = q; i < RED_BLKS; i += 4) s += mid[(size_t)i * 64 + t];
    st2[q][t] = s;
    __syncthreads();
    if (tid < 64) st[tid] = st2[0][tid] + st2[1][tid] + st2[2][tid] + st2[3][tid];
    __syncthreads();
    if (tid < HID) {
        double invN = 1.0 / (double)N_NODES;
        double mu = st[tid] * invN;
        double var = st[HID + tid] * invN - mu * mu;
        double sc = (double)g2[tid] / sqrt(var + (double)BN_EPS);
        pPQ[tid] = (float)sc;
        pPQ[HID + tid] = (float)((double)be2[tid] - mu * sc);
    }
}

// ---------------- attentional pooling: block per graph ----------------
#define FIN_TPB 128
__launch_bounds__(FIN_TPB)
__global__ void k_final(const float* __restrict__ h2pre, const int* __restrict__ batch,
                        const float* __restrict__ pPQ, const float* __restrict__ gate_w,
                        const float* __restrict__ gate_b, const float* __restrict__ lin_w,
                        const float* __restrict__ lin_b, float* __restrict__ out) {
    __shared__ int sh_lo, sh_hi;
    __shared__ float red[2][HID + 2];
    __shared__ float sh_P[HID], sh_Q[HID], sh_gw[HID], sh_lw[HID];
    int g = blockIdx.x;
    if (threadIdx.x == 0) {
        int lo = 0, hi = N_NODES;
        while (lo < hi) { int mid = (lo + hi) >> 1; if (batch[mid] < g) lo = mid + 1; else hi = mid; }
        sh_lo = lo;
        int lo2 = lo, hi2 = N_NODES;
        int key2 = g + 1;
        while (lo2 < hi2) { int mid = (lo2 + hi2) >> 1; if (batch[mid] < key2) lo2 = mid + 1; else hi2 = mid; }
        sh_hi = lo2;
    }
    if (threadIdx.x < HID) {
        sh_P[threadIdx.x] = pPQ[threadIdx.x];
        sh_Q[threadIdx.x] = pPQ[HID + threadIdx.x];
        sh_gw[threadIdx.x] = gate_w[threadIdx.x];
        sh_lw[threadIdx.x] = lin_w[threadIdx.x];
    }
    __syncthreads();
    int lo = sh_lo, hi = sh_hi;
    float gb = gate_b[0];

    float mx = -3.0e38f;
    for (int n = lo + threadIdx.x; n < hi; n += FIN_TPB) {
        const float4* hp = (const float4*)(h2pre + (size_t)n * HID);
        float sc = gb;
#pragma unroll
        for (int i = 0; i < HID / 4; i++) {
            float4 v = hp[i];
            sc += relu_f(fmaf(v.x, sh_P[4 * i], sh_Q[4 * i])) * sh_gw[4 * i];
            sc += relu_f(fmaf(v.y, sh_P[4 * i + 1], sh_Q[4 * i + 1])) * sh_gw[4 * i + 1];
            sc += relu_f(fmaf(v.z, sh_P[4 * i + 2], sh_Q[4 * i + 2])) * sh_gw[4 * i + 2];
            sc += relu_f(fmaf(v.w, sh_P[4 * i + 3], sh_Q[4 * i + 3])) * sh_gw[4 * i + 3];
        }
        mx = fmaxf(mx, sc);
    }
    for (int o = 32; o; o >>= 1) mx = fmaxf(mx, __shfl_down(mx, o));
    if ((threadIdx.x & 63) == 0) red[threadIdx.x >> 6][0] = mx;
    __syncthreads();
    float smax = fmaxf(red[0][0], red[1][0]);
    __syncthreads();

    float S = 0.f;
    float T[HID];
#pragma unroll
    for (int f = 0; f < HID; f++) T[f] = 0.f;
    for (int n = lo + threadIdx.x; n < hi; n += FIN_TPB) {
        const float4* hp = (const float4*)(h2pre + (size_t)n * HID);
        float h[HID];
        float sc = gb;
#pragma unroll
        for (int i = 0; i < HID / 4; i++) {
            float4 v = hp[i];
            h[4 * i]     = relu_f(fmaf(v.x, sh_P[4 * i],     sh_Q[4 * i]));
            h[4 * i + 1] = relu_f(fmaf(v.y, sh_P[4 * i + 1], sh_Q[4 * i + 1]));
            h[4 * i + 2] = relu_f(fmaf(v.z, sh_P[4 * i + 2], sh_Q[4 * i + 2]));
            h[4 * i + 3] = relu_f(fmaf(v.w, sh_P[4 * i + 3], sh_Q[4 * i + 3]));
            sc += h[4 * i] * sh_gw[4 * i] + h[4 * i + 1] * sh_gw[4 * i + 1]
                + h[4 * i + 2] * sh_gw[4 * i + 2] + h[4 * i + 3] * sh_gw[4 * i + 3];
        }
        float e = __expf(sc - smax);
        S += e;
#pragma unroll
        for (int f = 0; f < HID; f++) T[f] += e * h[f];
    }
    for (int o = 32; o; o >>= 1) {
        S += __shfl_down(S, o);
#pragma unroll
        for (int f = 0; f < HID; f++) T[f] += __shfl_down(T[f], o);
    }
    if ((threadIdx.x & 63) == 0) {
        int w = threadIdx.x >> 6;
        red[w][1] = S;
#pragma unroll
        for (int f = 0; f < HID; f++) red[w][2 + f] = T[f];
    }
    __syncthreads();
    if (threadIdx.x == 0) {
        float St = red[0][1] + red[1][1];
        float z = lin_b[0];
        if (St > 0.f) {
            float inv = 1.f / St;
#pragma unroll
            for (int f = 0; f < HID; f++)
                z += (red[0][2 + f] + red[1][2 + f]) * inv * sh_lw[f];
        }
        out[g] = 1.f / (1.f + __expf(-z));
    }
}

extern "C" void kernel_launch(void* const* d_in, const int* in_sizes, int n_in,
                              void* d_out, int out_size, void* d_ws, size_t ws_size,
                              hipStream_t stream) {
    const float* x = (const float*)d_in[0];
    const int* ei = (const int*)d_in[1];       // int32 per harness convention
    const int* batch = (const int*)d_in[2];    // int32
    const float* W1l = (const float*)d_in[3];
    const float* b1l = (const float*)d_in[4];
    const float* W1r = (const float*)d_in[5];
    const float* W2l = (const float*)d_in[6];
    const float* b2l = (const float*)d_in[7];
    const float* W2r = (const float*)d_in[8];
    const float* g1 = (const float*)d_in[9];
    const float* be1 = (const float*)d_in[10];
    const float* g2 = (const float*)d_in[11];
    const float* be2 = (const float*)d_in[12];
    const float* gate_w = (const float*)d_in[13];
    const float* gate_b = (const float*)d_in[14];
    const float* lin_w = (const float*)d_in[15];
    const float* lin_b = (const float*)d_in[16];

    const int* srcp = ei;
    const int* dstp = ei + N_EDGES;

    char* ws = (char*)d_ws;
    size_t p = 0;
    auto alloc = [&](size_t bytes) -> char* {
        char* r = ws + p;
        p = (p + bytes + 255) & ~(size_t)255;
        return r;
    };
    unsigned int* ebuf = (unsigned int*)alloc((size_t)NBUCK * CAP * 4);  // 28.0 MB
    int* ebuf2 = (int*)alloc((size_t)NBUCK * CAP * 4);                   // 28.0 MB (sorted src)
    float* ax = (float*)alloc((size_t)N_NODES * 2 * 4);                  // 1.6 MB
    int* deg = (int*)alloc((size_t)N_NODES * 4);
    int* offs = (int*)alloc((size_t)N_NODES * 4);
    int* cursor = (int*)alloc((size_t)NBUCK * 4);
    float* pABC = (float*)alloc(96 * 4);
    float* pPQ = (float*)alloc(64 * 4);
    float* part1 = (float*)alloc((size_t)NBUCK * 8 * 4);
    float* part2 = (float*)alloc((size_t)NBLK_C * 64 * 4);               // 800 KB
    double* mid = (double*)alloc((size_t)RED_BLKS * 64 * 8);             // 32 KB
    float* h2pre = (float*)ebuf;  // alias: ebuf dead after k_sort; h2pre written in k_conv2

    k_init<<<1, 1024, 0, stream>>>(cursor);
    k_part<<<NPARTBLK, 256, 0, stream>>>(srcp, dstp, cursor, ebuf);
    k_sort<<<NBUCK, 256, 0, stream>>>(ebuf, cursor, x, ebuf2, deg, offs, ax, part1);
    k_params1<<<1, 256, 0, stream>>>(part1, W1l, b1l, W1r, g1, be1, pABC);
    k_conv2<<<NBLK_C, 256, 0, stream>>>(ebuf2, offs, deg, ax, pABC, W2l, W2r, b2l, h2pre, part2);
    k_red2<<<RED_BLKS, 256, 0, stream>>>(part2, mid);
    k_params2<<<1, 256, 0, stream>>>(mid, g2, be2, pPQ);
    k_final<<<N_GRAPHS, FIN_TPB, 0, stream>>>(h2pre, batch, pPQ, gate_w, gate_b, lin_w, lin_b,
                                              (float*)d_out);
}

// Round 14
// 482.153 us; speedup vs baseline: 1.1962x; 1.1962x over previous
//
#include <hip/hip_runtime.h>
#include <math.h>

#define N_NODES 200000
#define N_EDGES 6400000
#define N_GRAPHS 2048
#define HID 32
#define BN_EPS 1e-5f

#define NPB 256                                   // nodes per bucket (pow2) for part/sort
#define NBUCK ((N_NODES + NPB - 1) / NPB)         // 782
#define CAP 8960                                  // mean 8184 + ~8.6 sigma; 8960/256 = 35
#define PART_CHUNK 8192
#define NPARTBLK ((N_EDGES + PART_CHUNK - 1) / PART_CHUNK)  // 782

#define NPC 64                                    // nodes per conv2 block
#define NBLK_C (N_NODES / NPC)                    // 3125 (exact)

#define RED_BLKS 64                               // stage-1 reduction blocks for part2
#define RED_CHUNK ((NBLK_C + RED_BLKS - 1) / RED_BLKS)  // 49

__device__ inline float relu_f(float v) { return fmaxf(v, 0.f); }

// ---------------- cursor init ----------------
__global__ void k_init(int* __restrict__ cursor) {
    int t = blockIdx.x * blockDim.x + threadIdx.x;
    if (t < NBUCK) cursor[t] = t * CAP;
}

// ---------------- bucket partition: edges -> packed (src | local_dst<<18) ----------------
// int4 loads; rank captured in pass-1 histogram atomics -> pass-2 scatter is atomic-free.
__launch_bounds__(256)
__global__ void k_part(const int* __restrict__ src, const int* __restrict__ dst,
                       int* __restrict__ cursor, unsigned int* __restrict__ ebuf) {
    __shared__ int histL[NBUCK];
    __shared__ int baseL[NBUCK];
    int tid = threadIdx.x;
    for (int i = tid; i < NBUCK; i += 256) histL[i] = 0;
    __syncthreads();
    int e0 = blockIdx.x * PART_CHUNK;
    int e1 = min(e0 + PART_CHUNK, N_EDGES);
    int4 dreg[8];
    int4 rreg[8];
    // pass 1: histogram with rank capture (dst cached in registers)
#pragma unroll
    for (int i = 0; i < 8; i++) {
        int base = e0 + (i * 256 + tid) * 4;
        if (base < e1) {   // base,e1 both 4-aligned -> full int4 or nothing
            int4 d4 = *(const int4*)(dst + base);
            dreg[i] = d4;
            rreg[i].x = atomicAdd(&histL[d4.x >> 8], 1);
            rreg[i].y = atomicAdd(&histL[d4.y >> 8], 1);
            rreg[i].z = atomicAdd(&histL[d4.z >> 8], 1);
            rreg[i].w = atomicAdd(&histL[d4.w >> 8], 1);
        } else {
            dreg[i] = make_int4(-1, -1, -1, -1);
        }
    }
    __syncthreads();
    for (int i = tid; i < NBUCK; i += 256) {
        int c = histL[i];
        if (c) baseL[i] = atomicAdd(&cursor[i], c);
    }
    __syncthreads();
    // pass 2: scatter packed records (no atomics)
#pragma unroll
    for (int i = 0; i < 8; i++) {
        int base = e0 + (i * 256 + tid) * 4;
        if (base < e1) {
            int4 s4 = *(const int4*)(src + base);
            int4 d4 = dreg[i];
            int4 r4 = rreg[i];
            int b, pos;
            b = d4.x >> 8; pos = baseL[b] + r4.x;
            if (pos < (b + 1) * CAP) ebuf[pos] = (unsigned)(s4.x & 0x3FFFF) | ((unsigned)(d4.x & 255) << 18);
            b = d4.y >> 8; pos = baseL[b] + r4.y;
            if (pos < (b + 1) * CAP) ebuf[pos] = (unsigned)(s4.y & 0x3FFFF) | ((unsigned)(d4.y & 255) << 18);
            b = d4.z >> 8; pos = baseL[b] + r4.z;
            if (pos < (b + 1) * CAP) ebuf[pos] = (unsigned)(s4.z & 0x3FFFF) | ((unsigned)(d4.z & 255) << 18);
            b = d4.w >> 8; pos = baseL[b] + r4.w;
            if (pos < (b + 1) * CAP) ebuf[pos] = (unsigned)(s4.w & 0x3FFFF) | ((unsigned)(d4.w & 255) << 18);
        }
    }
}

// ---------------- counting sort within bucket + per-node x-sum + BN1 partials ----------------
// Rank captured in pass-1 histogram atomics -> scatter is atomic-free.
__launch_bounds__(256)
__global__ void k_sort(const unsigned int* __restrict__ ebuf, const int* __restrict__ cursor,
                       const float* __restrict__ x, int* __restrict__ ebuf2,
                       int* __restrict__ deg, int* __restrict__ offs,
                       float* __restrict__ ax, float* __restrict__ part1) {
    __shared__ int degL[NPB], scanL[NPB], offL[NPB];
    __shared__ float red[4][5];
    int tid = threadIdx.x;
    degL[tid] = 0;
    __syncthreads();
    int b = blockIdx.x;
    int p0 = b * CAP;
    int cnt = min(cursor[b] - p0, CAP);
    int rk[35];   // CAP/256 = 35
    // pass 1: histogram with rank capture
#pragma unroll
    for (int it = 0; it < 35; it++) {
        int i = tid + it * 256;
        if (i < cnt) rk[it] = atomicAdd(&degL[ebuf[p0 + i] >> 18], 1);
    }
    __syncthreads();
    int d = degL[tid];
    scanL[tid] = d;
    __syncthreads();
    for (int off = 1; off < NPB; off <<= 1) {
        int y = (tid >= off) ? scanL[tid - off] : 0;
        __syncthreads();
        scanL[tid] += y;
        __syncthreads();
    }
    int myoff = scanL[tid] - d;  // exclusive prefix
    offL[tid] = myoff;
    __syncthreads();
    int node = b * NPB + tid;
    if (node < N_NODES) { deg[node] = d; offs[node] = p0 + myoff; }
    // pass 2: scatter with captured ranks (ebuf re-read, L2-hot; no atomics)
#pragma unroll
    for (int it = 0; it < 35; it++) {
        int i = tid + it * 256;
        if (i < cnt) {
            unsigned v = ebuf[p0 + i];
            int ld = v >> 18;
            ebuf2[p0 + offL[ld] + rk[it]] = (int)(v & 0x3FFFF);
        }
    }
    __syncthreads();
    // per-node serial sum of x over sorted neighbor list (L2-hot, just written by this block)
    float sum = 0.f;
    int base = p0 + myoff;
    int j = 0;
    for (; j + 8 <= d; j += 8) {
        int ss[8];
#pragma unroll
        for (int k = 0; k < 8; k++) ss[k] = ebuf2[base + j + k];
        float acc = 0.f;
#pragma unroll
        for (int k = 0; k < 8; k++) acc += x[ss[k]];
        sum += acc;
    }
    for (; j < d; j++) sum += x[ebuf2[base + j]];
    float an = 0.f, xn = 0.f;
    if (node < N_NODES) {
        an = sum / (float)max(d, 1);
        xn = x[node];
        ax[2 * node] = an;
        ax[2 * node + 1] = xn;
    }
    float sa = an, sx = xn, saa = an * an, sxx = xn * xn, sax = an * xn;
    for (int o = 32; o; o >>= 1) {
        sa += __shfl_down(sa, o);
        sx += __shfl_down(sx, o);
        saa += __shfl_down(saa, o);
        sxx += __shfl_down(sxx, o);
        sax += __shfl_down(sax, o);
    }
    int w = tid >> 6;
    if ((tid & 63) == 0) {
        red[w][0] = sa; red[w][1] = sx; red[w][2] = saa; red[w][3] = sxx; red[w][4] = sax;
    }
    __syncthreads();
    if (tid < 5)
        part1[b * 8 + tid] = red[0][tid] + red[1][tid] + red[2][tid] + red[3][tid];
}

// ---------------- fold BN1: parallel fp64 reduction of partials ----------------
__launch_bounds__(256)
__global__ void k_params1(const float* __restrict__ part1,
                          const float* __restrict__ W1l, const float* __restrict__ b1l,
                          const float* __restrict__ W1r, const float* __restrict__ g1,
                          const float* __restrict__ be1, float* __restrict__ pABC) {
    int tid = threadIdx.x;
    double loc[5] = {0, 0, 0, 0, 0};
    for (int b = tid; b < NBUCK; b += 256) {
#pragma unroll
        for (int s = 0; s < 5; s++) loc[s] += (double)part1[b * 8 + s];
    }
    for (int o = 32; o; o >>= 1) {
#pragma unroll
        for (int s = 0; s < 5; s++) loc[s] += __shfl_down(loc[s], o);
    }
    __shared__ double red[4][5];
    __shared__ double st[5];
    int w = tid >> 6;
    if ((tid & 63) == 0) {
#pragma unroll
        for (int s = 0; s < 5; s++) red[w][s] = loc[s];
    }
    __syncthreads();
    if (tid < 5) st[tid] = red[0][tid] + red[1][tid] + red[2][tid] + red[3][tid];
    __syncthreads();
    int f = tid;
    if (f < HID) {
        double invN = 1.0 / (double)N_NODES;
        double ma = st[0] * invN, mx = st[1] * invN;
        double va = st[2] * invN - ma * ma;
        double vx = st[3] * invN - mx * mx;
        double cax = st[4] * invN - ma * mx;
        double wl = (double)W1l[f], wr = (double)W1r[f];
        double mu = wl * ma + wr * mx + (double)b1l[f];
        double var = wl * wl * va + wr * wr * vx + 2.0 * wl * wr * cax;
        double s = (double)g1[f] / sqrt(var + (double)BN_EPS);
        pABC[f] = (float)(wl * s);
        pABC[HID + f] = (float)(wr * s);
        pABC[2 * HID + f] = (float)(((double)b1l[f] - mu) * s + (double)be1[f]);
    }
}

// ---------------- conv2: paired-node gather + branch-free crunch + matmul + BN2 partials ----
__launch_bounds__(256)
__global__ void k_conv2(const int* __restrict__ ebuf2, const int* __restrict__ offs,
                        const int* __restrict__ deg, const float* __restrict__ ax,
                        const float* __restrict__ pABC,
                        const float* __restrict__ W2l, const float* __restrict__ W2r,
                        const float* __restrict__ b2l, float* __restrict__ h2pre,
                        float* __restrict__ part2) {
    __shared__ float aggL[NPC * (HID + 1)];              // stride 33 (8.25 KB)
    __shared__ __align__(16) float2 stageL[8][2][32];    // per-group A/B staging (4 KB)
    __shared__ float A_s[HID], B_s[HID], C_s[HID];
    __shared__ int degS[NPC], offS[NPC];
    int tid = threadIdx.x;
    int b = blockIdx.x;
    if (tid < HID) {
        A_s[tid] = pABC[tid];
        B_s[tid] = pABC[HID + tid];
        C_s[tid] = pABC[2 * HID + tid];
    }
    if (tid < NPC) {
        degS[tid] = deg[b * NPC + tid];
        offS[tid] = offs[b * NPC + tid];
    }
    __syncthreads();
    int f = tid & 31;                         // lane within group = feature in crunch
    int grp = tid >> 5;                       // 8 groups of 32 lanes
    float Af = A_s[f], Bf = B_s[f], Cf = C_s[f];
    float reluC = fmaxf(Cf, 0.f);
    const float2* ax2 = (const float2*)ax;
    float2* stA = stageL[grp][0];
    float2* stB = stageL[grp][1];
    const float4* stA4 = (const float4*)stA;
    const float4* stB4 = (const float4*)stB;
    // Phase A: 2 nodes per gather exposure; branch-free unrolled crunch with padding fixup.
#pragma unroll 1
    for (int p = 0; p < 4; p++) {
        int lnA = (2 * p) * 8 + grp;
        int lnB = (2 * p + 1) * 8 + grp;
        int dgA = degS[lnA], offA = offS[lnA];
        int dgB = degS[lnB], offB = offS[lnB];
        int rounds = (max(dgA, dgB) + 31) >> 5;
        float mA = 0.f, mB = 0.f;
#pragma unroll 1
        for (int r = 0; r < rounds; r++) {
            int j = r * 32;
            float2 pa = make_float2(0.f, 0.f), pb = make_float2(0.f, 0.f);
            if (f < dgA - j) pa = ax2[ebuf2[offA + j + f]];   // 2 independent 32-wide gathers
            if (f < dgB - j) pb = ax2[ebuf2[offB + j + f]];
            stA[f] = pa;
            stB[f] = pb;
#pragma unroll
            for (int u = 0; u < 16; u++) {                    // immediate-offset ds_read_b128
                float4 qa = stA4[u];
                mA += relu_f(fmaf(qa.x, Af, fmaf(qa.y, Bf, Cf)));
                mA += relu_f(fmaf(qa.z, Af, fmaf(qa.w, Bf, Cf)));
                float4 qb = stB4[u];
                mB += relu_f(fmaf(qb.x, Af, fmaf(qb.y, Bf, Cf)));
                mB += relu_f(fmaf(qb.z, Af, fmaf(qb.w, Bf, Cf)));
            }
        }
        // padded (0,0) slots each contributed exactly relu(Cf); subtract them out
        mA -= (float)(rounds * 32 - dgA) * reluC;
        mB -= (float)(rounds * 32 - dgB) * reluC;
        aggL[lnA * (HID + 1) + f] = mA / (float)max(dgA, 1);
        aggL[lnB * (HID + 1) + f] = mB / (float)max(dgB, 1);
    }
    __syncthreads();
    // Phase B: thread = (node = tid&63, feature octet = tid>>6); all 4 waves active
    int nl = tid & 63;
    int fg = tid >> 6;                        // 0..3, uniform per wave
    int node = b * NPC + nl;
    float2 axn = ax2[node];
    float an = axn.x, xn = axn.y;
    float ag[HID], h1[HID];
#pragma unroll
    for (int k = 0; k < HID; k++) {
        ag[k] = aggL[nl * (HID + 1) + k];
        h1[k] = relu_f(fmaf(an, A_s[k], fmaf(xn, B_s[k], C_s[k])));
    }
    float v[8];
#pragma unroll
    for (int lf = 0; lf < 8; lf++) {
        int ff = fg * 8 + lf;
        const float4* wl4 = (const float4*)(W2l + ff * HID);
        const float4* wr4 = (const float4*)(W2r + ff * HID);
        float s = b2l[ff];
#pragma unroll
        for (int q = 0; q < HID / 4; q++) {
            float4 wl = wl4[q], wr = wr4[q];
            s = fmaf(ag[4 * q],     wl.x, fmaf(h1[4 * q],     wr.x, s));
            s = fmaf(ag[4 * q + 1], wl.y, fmaf(h1[4 * q + 1], wr.y, s));
            s = fmaf(ag[4 * q + 2], wl.z, fmaf(h1[4 * q + 2], wr.z, s));
            s = fmaf(ag[4 * q + 3], wl.w, fmaf(h1[4 * q + 3], wr.w, s));
        }
        v[lf] = s;
    }
    // store: 4 threads per node cover the contiguous 32-float row (2 float4 each)
    float4* op = (float4*)(h2pre + (size_t)node * HID + fg * 8);
    op[0] = make_float4(v[0], v[1], v[2], v[3]);
    op[1] = make_float4(v[4], v[5], v[6], v[7]);
    // BN2 partials: wave-level reduce over 64 nodes for this wave's 8 features
#pragma unroll
    for (int lf = 0; lf < 8; lf++) {
        float s1v = v[lf], s2v = v[lf] * v[lf];
        for (int o = 32; o; o >>= 1) {
            s1v += __shfl_down(s1v, o);
            s2v += __shfl_down(s2v, o);
        }
        if (nl == 0) {
            part2[(size_t)b * 64 + fg * 8 + lf] = s1v;
            part2[(size_t)b * 64 + 32 + fg * 8 + lf] = s2v;
        }
    }
}

// ---------------- BN2 reduction stage 1: 64 blocks sum slices of part2 (fp64) ----------------
__launch_bounds__(256)
__global__ void k_red2(const float* __restrict__ part2, double* __restrict__ mid) {
    __shared__ double st2[4][64];
    int tid = threadIdx.x;
    int q = tid >> 6, t = tid & 63;
    int b0 = blockIdx.x * RED_CHUNK;
    int b1 = min(b0 + RED_CHUNK, NBLK_C);
    double s = 0.0;
    for (int b = b0 + q; b < b1; b += 4) s += (double)part2[(size_t)b * 64 + t];
    st2[q][t] = s;
    __syncthreads();
    if (tid < 64)
        mid[(size_t)blockIdx.x * 64 + tid] = st2[0][tid] + st2[1][tid] + st2[2][tid] + st2[3][tid];
}

// ---------------- fold BN2: stage 2 over 64x64 doubles ----------------
__launch_bounds__(256)
__global__ void k_params2(const double* __restrict__ mid, const float* __restrict__ g2,
                          const float* __restrict__ be2, float* __restrict__ pPQ) {
    __shared__ double st2[4][64];
    __shared__ double st[64];
    int tid = threadIdx.x;
    int q = tid >> 6, t = tid & 63;
    double s = 0.0;
    for (int i = q; i < RED_BLKS; i += 4) s += mid[(size_t)i * 64 + t];
    st2[q][t] = s;
    __syncthreads();
    if (tid < 64) st[tid] = st2[0][tid] + st2[1][tid] + st2[2][tid] + st2[3][tid];
    __syncthreads();
    if (tid < HID) {
        double invN = 1.0 / (double)N_NODES;
        double mu = st[tid] * invN;
        double var = st[HID + tid] * invN - mu * mu;
        double sc = (double)g2[tid] / sqrt(var + (double)BN_EPS);
        pPQ[tid] = (float)sc;
        pPQ[HID + tid] = (float)((double)be2[tid] - mu * sc);
    }
}

// ---------------- attentional pooling: block per graph ----------------
#define FIN_TPB 128
__launch_bounds__(FIN_TPB)
__global__ void k_final(const float* __restrict__ h2pre, const int* __restrict__ batch,
                        const float* __restrict__ pPQ, const float* __restrict__ gate_w,
                        const float* __restrict__ gate_b, const float* __restrict__ lin_w,
                        const float* __restrict__ lin_b, float* __restrict__ out) {
    __shared__ int sh_lo, sh_hi;
    __shared__ float red[2][HID + 2];
    __shared__ float sh_P[HID], sh_Q[HID], sh_gw[HID], sh_lw[HID];
    int g = blockIdx.x;
    if (threadIdx.x == 0) {
        int lo = 0, hi = N_NODES;
        while (lo < hi) { int mid = (lo + hi) >> 1; if (batch[mid] < g) lo = mid + 1; else hi = mid; }
        sh_lo = lo;
        int lo2 = lo, hi2 = N_NODES;
        int key2 = g + 1;
        while (lo2 < hi2) { int mid = (lo2 + hi2) >> 1; if (batch[mid] < key2) lo2 = mid + 1; else hi2 = mid; }
        sh_hi = lo2;
    }
    if (threadIdx.x < HID) {
        sh_P[threadIdx.x] = pPQ[threadIdx.x];
        sh_Q[threadIdx.x] = pPQ[HID + threadIdx.x];
        sh_gw[threadIdx.x] = gate_w[threadIdx.x];
        sh_lw[threadIdx.x] = lin_w[threadIdx.x];
    }
    __syncthreads();
    int lo = sh_lo, hi = sh_hi;
    float gb = gate_b[0];

    float mx = -3.0e38f;
    for (int n = lo + threadIdx.x; n < hi; n += FIN_TPB) {
        const float4* hp = (const float4*)(h2pre + (size_t)n * HID);
        float sc = gb;
#pragma unroll
        for (int i = 0; i < HID / 4; i++) {
            float4 v = hp[i];
            sc += relu_f(fmaf(v.x, sh_P[4 * i], sh_Q[4 * i])) * sh_gw[4 * i];
            sc += relu_f(fmaf(v.y, sh_P[4 * i + 1], sh_Q[4 * i + 1])) * sh_gw[4 * i + 1];
            sc += relu_f(fmaf(v.z, sh_P[4 * i + 2], sh_Q[4 * i + 2])) * sh_gw[4 * i + 2];
            sc += relu_f(fmaf(v.w, sh_P[4 * i + 3], sh_Q[4 * i + 3])) * sh_gw[4 * i + 3];
        }
        mx = fmaxf(mx, sc);
    }
    for (int o = 32; o; o >>= 1) mx = fmaxf(mx, __shfl_down(mx, o));
    if ((threadIdx.x & 63) == 0) red[threadIdx.x >> 6][0] = mx;
    __syncthreads();
    float smax = fmaxf(red[0][0], red[1][0]);
    __syncthreads();

    float S = 0.f;
    float T[HID];
#pragma unroll
    for (int f = 0; f < HID; f++) T[f] = 0.f;
    for (int n = lo + threadIdx.x; n < hi; n += FIN_TPB) {
        const float4* hp = (const float4*)(h2pre + (size_t)n * HID);
        float h[HID];
        float sc = gb;
#pragma unroll
        for (int i = 0; i < HID / 4; i++) {
            float4 v = hp[i];
            h[4 * i]     = relu_f(fmaf(v.x, sh_P[4 * i],     sh_Q[4 * i]));
            h[4 * i + 1] = relu_f(fmaf(v.y, sh_P[4 * i + 1], sh_Q[4 * i + 1]));
            h[4 * i + 2] = relu_f(fmaf(v.z, sh_P[4 * i + 2], sh_Q[4 * i + 2]));
            h[4 * i + 3] = relu_f(fmaf(v.w, sh_P[4 * i + 3], sh_Q[4 * i + 3]));
            sc += h[4 * i] * sh_gw[4 * i] + h[4 * i + 1] * sh_gw[4 * i + 1]
                + h[4 * i + 2] * sh_gw[4 * i + 2] + h[4 * i + 3] * sh_gw[4 * i + 3];
        }
        float e = __expf(sc - smax);
        S += e;
#pragma unroll
        for (int f = 0; f < HID; f++) T[f] += e * h[f];
    }
    for (int o = 32; o; o >>= 1) {
        S += __shfl_down(S, o);
#pragma unroll
        for (int f = 0; f < HID; f++) T[f] += __shfl_down(T[f], o);
    }
    if ((threadIdx.x & 63) == 0) {
        int w = threadIdx.x >> 6;
        red[w][1] = S;
#pragma unroll
        for (int f = 0; f < HID; f++) red[w][2 + f] = T[f];
    }
    __syncthreads();
    if (threadIdx.x == 0) {
        float St = red[0][1] + red[1][1];
        float z = lin_b[0];
        if (St > 0.f) {
            float inv = 1.f / St;
#pragma unroll
            for (int f = 0; f < HID; f++)
                z += (red[0][2 + f] + red[1][2 + f]) * inv * sh_lw[f];
        }
        out[g] = 1.f / (1.f + __expf(-z));
    }
}

extern "C" void kernel_launch(void* const* d_in, const int* in_sizes, int n_in,
                              void* d_out, int out_size, void* d_ws, size_t ws_size,
                              hipStream_t stream) {
    const float* x = (const float*)d_in[0];
    const int* ei = (const int*)d_in[1];       // int32 per harness convention
    const int* batch = (const int*)d_in[2];    // int32
    const float* W1l = (const float*)d_in[3];
    const float* b1l = (const float*)d_in[4];
    const float* W1r = (const float*)d_in[5];
    const float* W2l = (const float*)d_in[6];
    const float* b2l = (const float*)d_in[7];
    const float* W2r = (const float*)d_in[8];
    const float* g1 = (const float*)d_in[9];
    const float* be1 = (const float*)d_in[10];
    const float* g2 = (const float*)d_in[11];
    const float* be2 = (const float*)d_in[12];
    const float* gate_w = (const float*)d_in[13];
    const float* gate_b = (const float*)d_in[14];
    const float* lin_w = (const float*)d_in[15];
    const float* lin_b = (const float*)d_in[16];

    const int* srcp = ei;
    const int* dstp = ei + N_EDGES;

    char* ws = (char*)d_ws;
    size_t p = 0;
    auto alloc = [&](size_t bytes) -> char* {
        char* r = ws + p;
        p = (p + bytes + 255) & ~(size_t)255;
        return r;
    };
    unsigned int* ebuf = (unsigned int*)alloc((size_t)NBUCK * CAP * 4);  // 28.0 MB
    int* ebuf2 = (int*)alloc((size_t)NBUCK * CAP * 4);                   // 28.0 MB (sorted src)
    float* ax = (float*)alloc((size_t)N_NODES * 2 * 4);                  // 1.6 MB
    int* deg = (int*)alloc((size_t)N_NODES * 4);
    int* offs = (int*)alloc((size_t)N_NODES * 4);
    int* cursor = (int*)alloc((size_t)NBUCK * 4);
    float* pABC = (float*)alloc(96 * 4);
    float* pPQ = (float*)alloc(64 * 4);
    float* part1 = (float*)alloc((size_t)NBUCK * 8 * 4);
    float* part2 = (float*)alloc((size_t)NBLK_C * 64 * 4);               // 800 KB
    double* mid = (double*)alloc((size_t)RED_BLKS * 64 * 8);             // 32 KB
    float* h2pre = (float*)ebuf;  // alias: ebuf dead after k_sort; h2pre written in k_conv2

    k_init<<<1, 1024, 0, stream>>>(cursor);
    k_part<<<NPARTBLK, 256, 0, stream>>>(srcp, dstp, cursor, ebuf);
    k_sort<<<NBUCK, 256, 0, stream>>>(ebuf, cursor, x, ebuf2, deg, offs, ax, part1);
    k_params1<<<1, 256, 0, stream>>>(part1, W1l, b1l, W1r, g1, be1, pABC);
    k_conv2<<<NBLK_C, 256, 0, stream>>>(ebuf2, offs, deg, ax, pABC, W2l, W2r, b2l, h2pre, part2);
    k_red2<<<RED_BLKS, 256, 0, stream>>>(part2, mid);
    k_params2<<<1, 256, 0, stream>>>(mid, g2, be2, pPQ);
    k_final<<<N_GRAPHS, FIN_TPB, 0, stream>>>(h2pre, batch, pPQ, gate_w, gate_b, lin_w, lin_b,
                                              (float*)d_out);
}

// Round 15
// 478.909 us; speedup vs baseline: 1.2043x; 1.0068x over previous
//
#include <hip/hip_runtime.h>
#include <math.h>

#define N_NODES 200000
#define N_EDGES 6400000
#define N_GRAPHS 2048
#define HID 32
#define BN_EPS 1e-5f

#define NPB 256                                   // nodes per bucket (pow2) for part/sort
#define NBUCK ((N_NODES + NPB - 1) / NPB)         // 782
#define CAP 8960                                  // mean 8184 + ~8.6 sigma; 8960/256 = 35
#define PART_CHUNK 8192
#define NPARTBLK ((N_EDGES + PART_CHUNK - 1) / PART_CHUNK)  // 782

#define NPC 64                                    // nodes per conv2 block
#define NBLK_C (N_NODES / NPC)                    // 3125 (exact)

#define RED_BLKS 64                               // stage-1 reduction blocks for part2
#define RED_CHUNK ((NBLK_C + RED_BLKS - 1) / RED_BLKS)  // 49

__device__ inline float relu_f(float v) { return fmaxf(v, 0.f); }

// ---------------- cursor init ----------------
__global__ void k_init(int* __restrict__ cursor) {
    int t = blockIdx.x * blockDim.x + threadIdx.x;
    if (t < NBUCK) cursor[t] = t * CAP;
}

// ---------------- bucket partition: edges -> packed (src | local_dst<<18) ----------------
// int4 loads; rank captured in pass-1 histogram atomics -> pass-2 scatter is atomic-free.
__launch_bounds__(256)
__global__ void k_part(const int* __restrict__ src, const int* __restrict__ dst,
                       int* __restrict__ cursor, unsigned int* __restrict__ ebuf) {
    __shared__ int histL[NBUCK];
    __shared__ int baseL[NBUCK];
    int tid = threadIdx.x;
    for (int i = tid; i < NBUCK; i += 256) histL[i] = 0;
    __syncthreads();
    int e0 = blockIdx.x * PART_CHUNK;
    int e1 = min(e0 + PART_CHUNK, N_EDGES);
    int4 dreg[8];
    int4 rreg[8];
    // pass 1: histogram with rank capture (dst cached in registers)
#pragma unroll
    for (int i = 0; i < 8; i++) {
        int base = e0 + (i * 256 + tid) * 4;
        if (base < e1) {   // base,e1 both 4-aligned -> full int4 or nothing
            int4 d4 = *(const int4*)(dst + base);
            dreg[i] = d4;
            rreg[i].x = atomicAdd(&histL[d4.x >> 8], 1);
            rreg[i].y = atomicAdd(&histL[d4.y >> 8], 1);
            rreg[i].z = atomicAdd(&histL[d4.z >> 8], 1);
            rreg[i].w = atomicAdd(&histL[d4.w >> 8], 1);
        } else {
            dreg[i] = make_int4(-1, -1, -1, -1);
        }
    }
    __syncthreads();
    for (int i = tid; i < NBUCK; i += 256) {
        int c = histL[i];
        if (c) baseL[i] = atomicAdd(&cursor[i], c);
    }
    __syncthreads();
    // pass 2: scatter packed records (no atomics)
#pragma unroll
    for (int i = 0; i < 8; i++) {
        int base = e0 + (i * 256 + tid) * 4;
        if (base < e1) {
            int4 s4 = *(const int4*)(src + base);
            int4 d4 = dreg[i];
            int4 r4 = rreg[i];
            int b, pos;
            b = d4.x >> 8; pos = baseL[b] + r4.x;
            if (pos < (b + 1) * CAP) ebuf[pos] = (unsigned)(s4.x & 0x3FFFF) | ((unsigned)(d4.x & 255) << 18);
            b = d4.y >> 8; pos = baseL[b] + r4.y;
            if (pos < (b + 1) * CAP) ebuf[pos] = (unsigned)(s4.y & 0x3FFFF) | ((unsigned)(d4.y & 255) << 18);
            b = d4.z >> 8; pos = baseL[b] + r4.z;
            if (pos < (b + 1) * CAP) ebuf[pos] = (unsigned)(s4.z & 0x3FFFF) | ((unsigned)(d4.z & 255) << 18);
            b = d4.w >> 8; pos = baseL[b] + r4.w;
            if (pos < (b + 1) * CAP) ebuf[pos] = (unsigned)(s4.w & 0x3FFFF) | ((unsigned)(d4.w & 255) << 18);
        }
    }
}

// ---------------- counting sort within bucket + per-node x-sum + BN1 partials ----------------
// Rank captured in pass-1 histogram atomics -> scatter is atomic-free.
__launch_bounds__(256)
__global__ void k_sort(const unsigned int* __restrict__ ebuf, const int* __restrict__ cursor,
                       const float* __restrict__ x, int* __restrict__ ebuf2,
                       int* __restrict__ deg, int* __restrict__ offs,
                       float* __restrict__ ax, float* __restrict__ part1) {
    __shared__ int degL[NPB], scanL[NPB], offL[NPB];
    __shared__ float red[4][5];
    int tid = threadIdx.x;
    degL[tid] = 0;
    __syncthreads();
    int b = blockIdx.x;
    int p0 = b * CAP;
    int cnt = min(cursor[b] - p0, CAP);
    int rk[35];   // CAP/256 = 35
    // pass 1: histogram with rank capture
#pragma unroll
    for (int it = 0; it < 35; it++) {
        int i = tid + it * 256;
        if (i < cnt) rk[it] = atomicAdd(&degL[ebuf[p0 + i] >> 18], 1);
    }
    __syncthreads();
    int d = degL[tid];
    scanL[tid] = d;
    __syncthreads();
    for (int off = 1; off < NPB; off <<= 1) {
        int y = (tid >= off) ? scanL[tid - off] : 0;
        __syncthreads();
        scanL[tid] += y;
        __syncthreads();
    }
    int myoff = scanL[tid] - d;  // exclusive prefix
    offL[tid] = myoff;
    __syncthreads();
    int node = b * NPB + tid;
    if (node < N_NODES) { deg[node] = d; offs[node] = p0 + myoff; }
    // pass 2: scatter with captured ranks (ebuf re-read, L2-hot; no atomics)
#pragma unroll
    for (int it = 0; it < 35; it++) {
        int i = tid + it * 256;
        if (i < cnt) {
            unsigned v = ebuf[p0 + i];
            int ld = v >> 18;
            ebuf2[p0 + offL[ld] + rk[it]] = (int)(v & 0x3FFFF);
        }
    }
    __syncthreads();
    // per-node serial sum of x over sorted neighbor list (L2-hot, just written by this block)
    float sum = 0.f;
    int base = p0 + myoff;
    int j = 0;
    for (; j + 8 <= d; j += 8) {
        int ss[8];
#pragma unroll
        for (int k = 0; k < 8; k++) ss[k] = ebuf2[base + j + k];
        float acc = 0.f;
#pragma unroll
        for (int k = 0; k < 8; k++) acc += x[ss[k]];
        sum += acc;
    }
    for (; j < d; j++) sum += x[ebuf2[base + j]];
    float an = 0.f, xn = 0.f;
    if (node < N_NODES) {
        an = sum / (float)max(d, 1);
        xn = x[node];
        ax[2 * node] = an;
        ax[2 * node + 1] = xn;
    }
    float sa = an, sx = xn, saa = an * an, sxx = xn * xn, sax = an * xn;
    for (int o = 32; o; o >>= 1) {
        sa += __shfl_down(sa, o);
        sx += __shfl_down(sx, o);
        saa += __shfl_down(saa, o);
        sxx += __shfl_down(sxx, o);
        sax += __shfl_down(sax, o);
    }
    int w = tid >> 6;
    if ((tid & 63) == 0) {
        red[w][0] = sa; red[w][1] = sx; red[w][2] = saa; red[w][3] = sxx; red[w][4] = sax;
    }
    __syncthreads();
    if (tid < 5)
        part1[b * 8 + tid] = red[0][tid] + red[1][tid] + red[2][tid] + red[3][tid];
}

// ---------------- fold BN1: parallel fp64 reduction of partials ----------------
__launch_bounds__(256)
__global__ void k_params1(const float* __restrict__ part1,
                          const float* __restrict__ W1l, const float* __restrict__ b1l,
                          const float* __restrict__ W1r, const float* __restrict__ g1,
                          const float* __restrict__ be1, float* __restrict__ pABC) {
    int tid = threadIdx.x;
    double loc[5] = {0, 0, 0, 0, 0};
    for (int b = tid; b < NBUCK; b += 256) {
#pragma unroll
        for (int s = 0; s < 5; s++) loc[s] += (double)part1[b * 8 + s];
    }
    for (int o = 32; o; o >>= 1) {
#pragma unroll
        for (int s = 0; s < 5; s++) loc[s] += __shfl_down(loc[s], o);
    }
    __shared__ double red[4][5];
    __shared__ double st[5];
    int w = tid >> 6;
    if ((tid & 63) == 0) {
#pragma unroll
        for (int s = 0; s < 5; s++) red[w][s] = loc[s];
    }
    __syncthreads();
    if (tid < 5) st[tid] = red[0][tid] + red[1][tid] + red[2][tid] + red[3][tid];
    __syncthreads();
    int f = tid;
    if (f < HID) {
        double invN = 1.0 / (double)N_NODES;
        double ma = st[0] * invN, mx = st[1] * invN;
        double va = st[2] * invN - ma * ma;
        double vx = st[3] * invN - mx * mx;
        double cax = st[4] * invN - ma * mx;
        double wl = (double)W1l[f], wr = (double)W1r[f];
        double mu = wl * ma + wr * mx + (double)b1l[f];
        double var = wl * wl * va + wr * wr * vx + 2.0 * wl * wr * cax;
        double s = (double)g1[f] / sqrt(var + (double)BN_EPS);
        pABC[f] = (float)(wl * s);
        pABC[HID + f] = (float)(wr * s);
        pABC[2 * HID + f] = (float)(((double)b1l[f] - mu) * s + (double)be1[f]);
    }
}

// ---------------- conv2: quad-node gather + branch-free crunch + matmul + BN2 partials ----
__launch_bounds__(256)
__global__ void k_conv2(const int* __restrict__ ebuf2, const int* __restrict__ offs,
                        const int* __restrict__ deg, const float* __restrict__ ax,
                        const float* __restrict__ pABC,
                        const float* __restrict__ W2l, const float* __restrict__ W2r,
                        const float* __restrict__ b2l, float* __restrict__ h2pre,
                        float* __restrict__ part2) {
    __shared__ float aggL[NPC * (HID + 1)];              // stride 33 (8.25 KB)
    __shared__ __align__(16) float2 stageL[8][4][32];    // per-group A/B/C/D staging (8 KB)
    __shared__ float A_s[HID], B_s[HID], C_s[HID];
    __shared__ int degS[NPC], offS[NPC];
    int tid = threadIdx.x;
    int b = blockIdx.x;
    if (tid < HID) {
        A_s[tid] = pABC[tid];
        B_s[tid] = pABC[HID + tid];
        C_s[tid] = pABC[2 * HID + tid];
    }
    if (tid < NPC) {
        degS[tid] = deg[b * NPC + tid];
        offS[tid] = offs[b * NPC + tid];
    }
    __syncthreads();
    int f = tid & 31;                         // lane within group = feature in crunch
    int grp = tid >> 5;                       // 8 groups of 32 lanes
    float Af = A_s[f], Bf = B_s[f], Cf = C_s[f];
    float reluC = fmaxf(Cf, 0.f);
    const float2* ax2 = (const float2*)ax;
    float2* stA = stageL[grp][0];
    float2* stB = stageL[grp][1];
    float2* stC = stageL[grp][2];
    float2* stD = stageL[grp][3];
    const float4* stA4 = (const float4*)stA;
    const float4* stB4 = (const float4*)stB;
    const float4* stC4 = (const float4*)stC;
    const float4* stD4 = (const float4*)stD;
    // Phase A: 4 nodes per gather exposure (4 independent chains); branch-free crunch +
    // exact padding fixup.
#pragma unroll 1
    for (int p = 0; p < 2; p++) {
        int lnA = (4 * p) * 8 + grp;
        int lnB = (4 * p + 1) * 8 + grp;
        int lnC = (4 * p + 2) * 8 + grp;
        int lnD = (4 * p + 3) * 8 + grp;
        int dgA = degS[lnA], offA = offS[lnA];
        int dgB = degS[lnB], offB = offS[lnB];
        int dgC = degS[lnC], offC = offS[lnC];
        int dgD = degS[lnD], offD = offS[lnD];
        int rounds = (max(max(dgA, dgB), max(dgC, dgD)) + 31) >> 5;
        float mA = 0.f, mB = 0.f, mC = 0.f, mD = 0.f;
#pragma unroll 1
        for (int r = 0; r < rounds; r++) {
            int j = r * 32;
            float2 pa = make_float2(0.f, 0.f), pb = make_float2(0.f, 0.f);
            float2 pc = make_float2(0.f, 0.f), pd = make_float2(0.f, 0.f);
            if (f < dgA - j) pa = ax2[ebuf2[offA + j + f]];   // 4 independent 32-wide gathers
            if (f < dgB - j) pb = ax2[ebuf2[offB + j + f]];
            if (f < dgC - j) pc = ax2[ebuf2[offC + j + f]];
            if (f < dgD - j) pd = ax2[ebuf2[offD + j + f]];
            stA[f] = pa;
            stB[f] = pb;
            stC[f] = pc;
            stD[f] = pd;
#pragma unroll
            for (int u = 0; u < 16; u++) {                    // immediate-offset ds_read_b128
                float4 qa = stA4[u];
                mA += relu_f(fmaf(qa.x, Af, fmaf(qa.y, Bf, Cf)));
                mA += relu_f(fmaf(qa.z, Af, fmaf(qa.w, Bf, Cf)));
                float4 qb = stB4[u];
                mB += relu_f(fmaf(qb.x, Af, fmaf(qb.y, Bf, Cf)));
                mB += relu_f(fmaf(qb.z, Af, fmaf(qb.w, Bf, Cf)));
                float4 qc = stC4[u];
                mC += relu_f(fmaf(qc.x, Af, fmaf(qc.y, Bf, Cf)));
                mC += relu_f(fmaf(qc.z, Af, fmaf(qc.w, Bf, Cf)));
                float4 qd = stD4[u];
                mD += relu_f(fmaf(qd.x, Af, fmaf(qd.y, Bf, Cf)));
                mD += relu_f(fmaf(qd.z, Af, fmaf(qd.w, Bf, Cf)));
            }
        }
        // padded (0,0) slots each contributed exactly relu(Cf); subtract them out
        mA -= (float)(rounds * 32 - dgA) * reluC;
        mB -= (float)(rounds * 32 - dgB) * reluC;
        mC -= (float)(rounds * 32 - dgC) * reluC;
        mD -= (float)(rounds * 32 - dgD) * reluC;
        aggL[lnA * (HID + 1) + f] = mA / (float)max(dgA, 1);
        aggL[lnB * (HID + 1) + f] = mB / (float)max(dgB, 1);
        aggL[lnC * (HID + 1) + f] = mC / (float)max(dgC, 1);
        aggL[lnD * (HID + 1) + f] = mD / (float)max(dgD, 1);
    }
    __syncthreads();
    // Phase B: thread = (node = tid&63, feature octet = tid>>6); all 4 waves active
    int nl = tid & 63;
    int fg = tid >> 6;                        // 0..3, uniform per wave
    int node = b * NPC + nl;
    float2 axn = ax2[node];
    float an = axn.x, xn = axn.y;
    float ag[HID], h1[HID];
#pragma unroll
    for (int k = 0; k < HID; k++) {
        ag[k] = aggL[nl * (HID + 1) + k];
        h1[k] = relu_f(fmaf(an, A_s[k], fmaf(xn, B_s[k], C_s[k])));
    }
    float v[8];
#pragma unroll
    for (int lf = 0; lf < 8; lf++) {
        int ff = fg * 8 + lf;
        const float4* wl4 = (const float4*)(W2l + ff * HID);
        const float4* wr4 = (const float4*)(W2r + ff * HID);
        float s = b2l[ff];
#pragma unroll
        for (int q = 0; q < HID / 4; q++) {
            float4 wl = wl4[q], wr = wr4[q];
            s = fmaf(ag[4 * q],     wl.x, fmaf(h1[4 * q],     wr.x, s));
            s = fmaf(ag[4 * q + 1], wl.y, fmaf(h1[4 * q + 1], wr.y, s));
            s = fmaf(ag[4 * q + 2], wl.z, fmaf(h1[4 * q + 2], wr.z, s));
            s = fmaf(ag[4 * q + 3], wl.w, fmaf(h1[4 * q + 3], wr.w, s));
        }
        v[lf] = s;
    }
    // store: 4 threads per node cover the contiguous 32-float row (2 float4 each)
    float4* op = (float4*)(h2pre + (size_t)node * HID + fg * 8);
    op[0] = make_float4(v[0], v[1], v[2], v[3]);
    op[1] = make_float4(v[4], v[5], v[6], v[7]);
    // BN2 partials: wave-level reduce over 64 nodes for this wave's 8 features
#pragma unroll
    for (int lf = 0; lf < 8; lf++) {
        float s1v = v[lf], s2v = v[lf] * v[lf];
        for (int o = 32; o; o >>= 1) {
            s1v += __shfl_down(s1v, o);
            s2v += __shfl_down(s2v, o);
        }
        if (nl == 0) {
            part2[(size_t)b * 64 + fg * 8 + lf] = s1v;
            part2[(size_t)b * 64 + 32 + fg * 8 + lf] = s2v;
        }
    }
}

// ---------------- BN2 reduction stage 1: 64 blocks sum slices of part2 (fp64) ----------------
__launch_bounds__(256)
__global__ void k_red2(const float* __restrict__ part2, double* __restrict__ mid) {
    __shared__ double st2[4][64];
    int tid = threadIdx.x;
    int q = tid >> 6, t = tid & 63;
    int b0 = blockIdx.x * RED_CHUNK;
    int b1 = min(b0 + RED_CHUNK, NBLK_C);
    double s = 0.0;
    for (int b = b0 + q; b < b1; b += 4) s += (double)part2[(size_t)b * 64 + t];
    st2[q][t] = s;
    __syncthreads();
    if (tid < 64)
        mid[(size_t)blockIdx.x * 64 + tid] = st2[0][tid] + st2[1][tid] + st2[2][tid] + st2[3][tid];
}

// ---------------- attentional pooling: block per graph (BN2 fold inlined) ----------------
#define FIN_TPB 128
__launch_bounds__(FIN_TPB)
__global__ void k_final(const float* __restrict__ h2pre, const int* __restrict__ batch,
                        const double* __restrict__ mid, const float* __restrict__ g2,
                        const float* __restrict__ be2, const float* __restrict__ gate_w,
                        const float* __restrict__ gate_b, const float* __restrict__ lin_w,
                        const float* __restrict__ lin_b, float* __restrict__ out) {
    __shared__ int sh_lo, sh_hi;
    __shared__ float red[2][HID + 2];
    __shared__ float sh_P[HID], sh_Q[HID], sh_gw[HID], sh_lw[HID];
    __shared__ double md2[2][64];
    __shared__ double mst[64];
    int g = blockIdx.x;
    int tid = threadIdx.x;
    // inline BN2 fold: reduce mid[64][64] (L2-hot) -> pPQ in shared
    {
        int t = tid & 63, q = tid >> 6;       // q in 0..1
        double s = 0.0;
        for (int i = q; i < RED_BLKS; i += 2) s += mid[(size_t)i * 64 + t];
        md2[q][t] = s;
    }
    if (tid == 0) {
        int lo = 0, hi = N_NODES;
        while (lo < hi) { int mid2 = (lo + hi) >> 1; if (batch[mid2] < g) lo = mid2 + 1; else hi = mid2; }
        sh_lo = lo;
        int lo2 = lo, hi2 = N_NODES;
        int key2 = g + 1;
        while (lo2 < hi2) { int mid2 = (lo2 + hi2) >> 1; if (batch[mid2] < key2) lo2 = mid2 + 1; else hi2 = mid2; }
        sh_hi = lo2;
    }
    __syncthreads();
    if (tid < 64) mst[tid] = md2[0][tid] + md2[1][tid];
    __syncthreads();
    if (tid < HID) {
        double invN = 1.0 / (double)N_NODES;
        double mu = mst[tid] * invN;
        double var = mst[HID + tid] * invN - mu * mu;
        double sc = (double)g2[tid] / sqrt(var + (double)BN_EPS);
        sh_P[tid] = (float)sc;
        sh_Q[tid] = (float)((double)be2[tid] - mu * sc);
        sh_gw[tid] = gate_w[tid];
        sh_lw[tid] = lin_w[tid];
    }
    __syncthreads();
    int lo = sh_lo, hi = sh_hi;
    float gb = gate_b[0];

    float mx = -3.0e38f;
    for (int n = lo + tid; n < hi; n += FIN_TPB) {
        const float4* hp = (const float4*)(h2pre + (size_t)n * HID);
        float sc = gb;
#pragma unroll
        for (int i = 0; i < HID / 4; i++) {
            float4 v = hp[i];
            sc += relu_f(fmaf(v.x, sh_P[4 * i], sh_Q[4 * i])) * sh_gw[4 * i];
            sc += relu_f(fmaf(v.y, sh_P[4 * i + 1], sh_Q[4 * i + 1])) * sh_gw[4 * i + 1];
            sc += relu_f(fmaf(v.z, sh_P[4 * i + 2], sh_Q[4 * i + 2])) * sh_gw[4 * i + 2];
            sc += relu_f(fmaf(v.w, sh_P[4 * i + 3], sh_Q[4 * i + 3])) * sh_gw[4 * i + 3];
        }
        mx = fmaxf(mx, sc);
    }
    for (int o = 32; o; o >>= 1) mx = fmaxf(mx, __shfl_down(mx, o));
    if ((tid & 63) == 0) red[tid >> 6][0] = mx;
    __syncthreads();
    float smax = fmaxf(red[0][0], red[1][0]);
    __syncthreads();

    float S = 0.f;
    float T[HID];
#pragma unroll
    for (int f = 0; f < HID; f++) T[f] = 0.f;
    for (int n = lo + tid; n < hi; n += FIN_TPB) {
        const float4* hp = (const float4*)(h2pre + (size_t)n * HID);
        float h[HID];
        float sc = gb;
#pragma unroll
        for (int i = 0; i < HID / 4; i++) {
            float4 v = hp[i];
            h[4 * i]     = relu_f(fmaf(v.x, sh_P[4 * i],     sh_Q[4 * i]));
            h[4 * i + 1] = relu_f(fmaf(v.y, sh_P[4 * i + 1], sh_Q[4 * i + 1]));
            h[4 * i + 2] = relu_f(fmaf(v.z, sh_P[4 * i + 2], sh_Q[4 * i + 2]));
            h[4 * i + 3] = relu_f(fmaf(v.w, sh_P[4 * i + 3], sh_Q[4 * i + 3]));
            sc += h[4 * i] * sh_gw[4 * i] + h[4 * i + 1] * sh_gw[4 * i + 1]
                + h[4 * i + 2] * sh_gw[4 * i + 2] + h[4 * i + 3] * sh_gw[4 * i + 3];
        }
        float e = __expf(sc - smax);
        S += e;
#pragma unroll
        for (int f = 0; f < HID; f++) T[f] += e * h[f];
    }
    for (int o = 32; o; o >>= 1) {
        S += __shfl_down(S, o);
#pragma unroll
        for (int f = 0; f < HID; f++) T[f] += __shfl_down(T[f], o);
    }
    if ((tid & 63) == 0) {
        int w = tid >> 6;
        red[w][1] = S;
#pragma unroll
        for (int f = 0; f < HID; f++) red[w][2 + f] = T[f];
    }
    __syncthreads();
    if (tid == 0) {
        float St = red[0][1] + red[1][1];
        float z = lin_b[0];
        if (St > 0.f) {
            float inv = 1.f / St;
#pragma unroll
            for (int f = 0; f < HID; f++)
                z += (red[0][2 + f] + red[1][2 + f]) * inv * sh_lw[f];
        }
        out[g] = 1.f / (1.f + __expf(-z));
    }
}

extern "C" void kernel_launch(void* const* d_in, const int* in_sizes, int n_in,
                              void* d_out, int out_size, void* d_ws, size_t ws_size,
                              hipStream_t stream) {
    const float* x = (const float*)d_in[0];
    const int* ei = (const int*)d_in[1];       // int32 per harness convention
    const int* batch = (const int*)d_in[2];    // int32
    const float* W1l = (const float*)d_in[3];
    const float* b1l = (const float*)d_in[4];
    const float* W1r = (const float*)d_in[5];
    const float* W2l = (const float*)d_in[6];
    const float* b2l = (const float*)d_in[7];
    const float* W2r = (const float*)d_in[8];
    const float* g1 = (const float*)d_in[9];
    const float* be1 = (const float*)d_in[10];
    const float* g2 = (const float*)d_in[11];
    const float* be2 = (const float*)d_in[12];
    const float* gate_w = (const float*)d_in[13];
    const float* gate_b = (const float*)d_in[14];
    const float* lin_w = (const float*)d_in[15];
    const float* lin_b = (const float*)d_in[16];

    const int* srcp = ei;
    const int* dstp = ei + N_EDGES;

    char* ws = (char*)d_ws;
    size_t p = 0;
    auto alloc = [&](size_t bytes) -> char* {
        char* r = ws + p;
        p = (p + bytes + 255) & ~(size_t)255;
        return r;
    };
    unsigned int* ebuf = (unsigned int*)alloc((size_t)NBUCK * CAP * 4);  // 28.0 MB
    int* ebuf2 = (int*)alloc((size_t)NBUCK * CAP * 4);                   // 28.0 MB (sorted src)
    float* ax = (float*)alloc((size_t)N_NODES * 2 * 4);                  // 1.6 MB
    int* deg = (int*)alloc((size_t)N_NODES * 4);
    int* offs = (int*)alloc((size_t)N_NODES * 4);
    int* cursor = (int*)alloc((size_t)NBUCK * 4);
    float* pABC = (float*)alloc(96 * 4);
    float* part1 = (float*)alloc((size_t)NBUCK * 8 * 4);
    float* part2 = (float*)alloc((size_t)NBLK_C * 64 * 4);               // 800 KB
    double* mid = (double*)alloc((size_t)RED_BLKS * 64 * 8);             // 32 KB
    float* h2pre = (float*)ebuf;  // alias: ebuf dead after k_sort; h2pre written in k_conv2

    k_init<<<1, 1024, 0, stream>>>(cursor);
    k_part<<<NPARTBLK, 256, 0, stream>>>(srcp, dstp, cursor, ebuf);
    k_sort<<<NBUCK, 256, 0, stream>>>(ebuf, cursor, x, ebuf2, deg, offs, ax, part1);
    k_params1<<<1, 256, 0, stream>>>(part1, W1l, b1l, W1r, g1, be1, pABC);
    k_conv2<<<NBLK_C, 256, 0, stream>>>(ebuf2, offs, deg, ax, pABC, W2l, W2r, b2l, h2pre, part2);
    k_red2<<<RED_BLKS, 256, 0, stream>>>(part2, mid);
    k_final<<<N_GRAPHS, FIN_TPB, 0, stream>>>(h2pre, batch, mid, g2, be2, gate_w, gate_b,
                                              lin_w, lin_b, (float*)d_out);
}